// Round 1
// baseline (316.646 us; speedup 1.0000x reference)
//
#include <hip/hip_runtime.h>

#define K_CODES 4096
#define DIM 256
#define SEQ 2048
#define NTOK 65536

typedef __bf16 bf16x8 __attribute__((ext_vector_type(8)));
typedef float floatx4 __attribute__((ext_vector_type(4)));
typedef unsigned short u16x8 __attribute__((ext_vector_type(8)));
typedef unsigned short u16x4 __attribute__((ext_vector_type(4)));

__device__ __forceinline__ unsigned short f2bf(float f) {
    union { float f; unsigned int u; } v; v.f = f;
    unsigned int u = v.u;
    unsigned int r = u + 0x7fffu + ((u >> 16) & 1u);   // RNE
    return (unsigned short)(r >> 16);
}

// ---------------- kernel 1: code norms + bf16 codebook + zero loss slot ----
__global__ __launch_bounds__(256) void k_prep(const float* __restrict__ cb,
        unsigned short* __restrict__ cb_bf, float* __restrict__ norms,
        float* __restrict__ loss_slot) {
    const int w = threadIdx.x >> 6;
    const int lane = threadIdx.x & 63;
    const int code = blockIdx.x * 4 + w;
    floatx4 v = *(const floatx4*)(cb + code * DIM + lane * 4);
    float s = v[0]*v[0] + v[1]*v[1] + v[2]*v[2] + v[3]*v[3];
    u16x4 p;
    p[0] = f2bf(v[0]); p[1] = f2bf(v[1]); p[2] = f2bf(v[2]); p[3] = f2bf(v[3]);
    *(u16x4*)(cb_bf + code * DIM + lane * 4) = p;
    for (int off = 32; off; off >>= 1) s += __shfl_xor(s, off);
    if (lane == 0) norms[code] = s;
    if (blockIdx.x == 0 && threadIdx.x == 0) *loss_slot = 0.0f;
}

// ---------------- kernel 2: MFMA distance GEMM + argmin ---------------------
// block: 256 thr = 4 waves, 128 tokens (wave w: tokens tok0 + (w>>1)*64 + (w&1)*32 .. +31)
// LDS: 16896 ushorts, unioned: X-stage half (64 tok x 264) then cb ring 2 x (32 codes x 264)
__global__ __launch_bounds__(256) void k_argmin(const float* __restrict__ x,
        const unsigned short* __restrict__ cb_bf, const float* __restrict__ norms,
        int* __restrict__ out_idx) {
    __shared__ __align__(16) unsigned short smem[16896];
    const int t = threadIdx.x;
    const int lane = t & 63, w = t >> 6;
    const int tok0 = blockIdx.x * 128;
    const int b = tok0 >> 11;
    const int s0 = tok0 & 2047;
    const float* xin = x + (size_t)b * DIM * SEQ;

    // ---- stage X halves (as -2x in bf16), load A fragments
    bf16x8 af[2][8];
    const int col = lane & 15;
    const int quad = lane >> 4;
    for (int h = 0; h < 2; ++h) {
        for (int iter = 0; iter < 16; ++iter) {
            int d  = iter * 16 + (t >> 4);
            int so = (t & 15) * 4;
            floatx4 v = *(const floatx4*)(xin + d * SEQ + s0 + h * 64 + so);
            #pragma unroll
            for (int i = 0; i < 4; ++i)
                smem[(so + i) * 264 + d] = f2bf(-2.0f * v[i]);
        }
        __syncthreads();
        if ((w >> 1) == h) {
            int row = (w & 1) * 32 + col;
            #pragma unroll
            for (int m = 0; m < 2; ++m)
                #pragma unroll
                for (int ks = 0; ks < 8; ++ks)
                    af[m][ks] = *(const bf16x8*)&smem[(row + m * 16) * 264 + quad * 8 + ks * 32];
        }
        __syncthreads();
    }

    float minv[2][4]; int mini[2][4];
    #pragma unroll
    for (int m = 0; m < 2; ++m)
        #pragma unroll
        for (int r = 0; r < 4; ++r) { minv[m][r] = 3.0e38f; mini[m][r] = 0; }

    const int scode = t >> 3;   // 0..31 code within chunk
    const int sseg  = t & 7;    // 8 x 64B segments per code row

    // stage chunk 0 -> buf 0
    {
        const u16x8* src = (const u16x8*)(cb_bf + (size_t)scode * 256 + sseg * 32);
        unsigned short* dst = &smem[scode * 264 + sseg * 32];
        #pragma unroll
        for (int i = 0; i < 4; ++i) ((u16x8*)dst)[i] = src[i];
    }

    for (int c = 0; c < 128; ++c) {
        __syncthreads();
        if (c + 1 < 128) {
            const u16x8* src = (const u16x8*)(cb_bf + ((size_t)(c + 1) * 32 + scode) * 256 + sseg * 32);
            unsigned short* dst = &smem[((c + 1) & 1) * 8448 + scode * 264 + sseg * 32];
            #pragma unroll
            for (int i = 0; i < 4; ++i) ((u16x8*)dst)[i] = src[i];
        }
        const unsigned short* buf = &smem[(c & 1) * 8448];
        #pragma unroll
        for (int ns = 0; ns < 2; ++ns) {
            const int cbase = c * 32 + ns * 16;
            float nv = norms[cbase + col];
            bf16x8 bfrag[8];
            #pragma unroll
            for (int ks = 0; ks < 8; ++ks)
                bfrag[ks] = *(const bf16x8*)&buf[(ns * 16 + col) * 264 + quad * 8 + ks * 32];
            floatx4 acc0 = {nv, nv, nv, nv};
            floatx4 acc1 = {nv, nv, nv, nv};
            #pragma unroll
            for (int ks = 0; ks < 8; ++ks) {
                acc0 = __builtin_amdgcn_mfma_f32_16x16x32_bf16(af[0][ks], bfrag[ks], acc0, 0, 0, 0);
                acc1 = __builtin_amdgcn_mfma_f32_16x16x32_bf16(af[1][ks], bfrag[ks], acc1, 0, 0, 0);
            }
            const int code = cbase + col;
            #pragma unroll
            for (int r = 0; r < 4; ++r) {
                if (acc0[r] < minv[0][r]) { minv[0][r] = acc0[r]; mini[0][r] = code; }
                if (acc1[r] < minv[1][r]) { minv[1][r] = acc1[r]; mini[1][r] = code; }
            }
        }
    }

    // ---- reduce across the 16 column-lanes, write indices
    #pragma unroll
    for (int m = 0; m < 2; ++m)
        #pragma unroll
        for (int r = 0; r < 4; ++r) {
            float mv = minv[m][r]; int mi = mini[m][r];
            #pragma unroll
            for (int off = 8; off >= 1; off >>= 1) {
                float ov = __shfl_xor(mv, off);
                int   oi = __shfl_xor(mi, off);
                if (ov < mv || (ov == mv && oi < mi)) { mv = ov; mi = oi; }
            }
            if (col == 0) {
                int token = tok0 + (w >> 1) * 64 + (w & 1) * 32 + m * 16 + quad * 4 + r;
                out_idx[token] = mi;
            }
        }
}

// ---------------- kernel 3: gather + transpose-store + fused loss -----------
__global__ __launch_bounds__(256) void k_gather(const float* __restrict__ x,
        const float* __restrict__ cb, const int* __restrict__ idx,
        float* __restrict__ out, float* __restrict__ loss_slot) {
    __shared__ __align__(16) float qs[256 * 36];   // [dim][token(32)+pad]
    __shared__ int sidx[32];
    __shared__ float wpart[4];
    const int t = threadIdx.x;
    const int tb = blockIdx.x * 32;
    const int b = tb >> 11, s0 = tb & 2047;
    if (t < 32) sidx[t] = idx[tb + t];
    __syncthreads();
    {
        int tl = t >> 3, seg = t & 7;
        const float* src = cb + (size_t)sidx[tl] * DIM;
        #pragma unroll
        for (int i = 0; i < 8; ++i) {
            int dim = i * 32 + seg * 4;
            floatx4 v = *(const floatx4*)(src + dim);
            #pragma unroll
            for (int j = 0; j < 4; ++j) qs[(dim + j) * 36 + tl] = v[j];
        }
    }
    __syncthreads();
    float acc = 0.0f;
    {
        int dl = t >> 3, j0 = (t & 7) * 4;
        #pragma unroll
        for (int p = 0; p < 8; ++p) {
            int d = p * 32 + dl;
            size_t g = (size_t)b * DIM * SEQ + (size_t)d * SEQ + s0 + j0;
            floatx4 xv = *(const floatx4*)(x + g);
            floatx4 qv = *(const floatx4*)&qs[d * 36 + j0];
            *(floatx4*)(out + g) = qv;
            floatx4 df = qv - xv;
            acc += df[0]*df[0] + df[1]*df[1] + df[2]*df[2] + df[3]*df[3];
        }
    }
    for (int off = 32; off; off >>= 1) acc += __shfl_xor(acc, off);
    if ((t & 63) == 0) wpart[t >> 6] = acc;
    __syncthreads();
    if (t == 0) {
        float tot = wpart[0] + wpart[1] + wpart[2] + wpart[3];
        atomicAdd(loss_slot, tot * (1.25f / 16777216.0f));
    }
}

extern "C" void kernel_launch(void* const* d_in, const int* in_sizes, int n_in,
                              void* d_out, int out_size, void* d_ws, size_t ws_size,
                              hipStream_t stream) {
    const float* inputs   = (const float*)d_in[0];
    const float* codebook = (const float*)d_in[1];
    float* out = (float*)d_out;
    unsigned short* cb_bf = (unsigned short*)d_ws;                                  // 2 MB
    float* norms = (float*)((char*)d_ws + (size_t)K_CODES * DIM * 2);               // 16 KB
    int* idxbuf  = (int*)((char*)d_ws + (size_t)K_CODES * DIM * 2 + K_CODES * 4);   // 256 KB
    float* loss_slot = out + (out_size - 1);

    hipLaunchKernelGGL(k_prep,   dim3(K_CODES / 4), dim3(256), 0, stream,
                       codebook, cb_bf, norms, loss_slot);
    hipLaunchKernelGGL(k_argmin, dim3(NTOK / 128),  dim3(256), 0, stream,
                       inputs, cb_bf, norms, idxbuf);
    hipLaunchKernelGGL(k_gather, dim3(NTOK / 32),   dim3(256), 0, stream,
                       inputs, codebook, idxbuf, out, loss_slot);
}